// Round 5
// baseline (143.802 us; speedup 1.0000x reference)
//
#include <hip/hip_runtime.h>

#define N_NODES 8192
#define E_RAW   65536
#define NSLOT   (2*E_RAW + N_NODES)   // 139264 slots
#define DEGCAP  48                    // max deg ~40 (binomial, 8-sigma safe)
#define LITER   2

typedef __attribute__((ext_vector_type(8))) short bf16x8;
typedef __attribute__((ext_vector_type(4))) short bf16x4;
typedef __attribute__((ext_vector_type(4))) float f32x4;
typedef unsigned short u16;

__device__ __forceinline__ u16 f2b(float f) {
  unsigned u = __float_as_uint(f);
  u = (u + 0x7FFFu + ((u >> 16) & 1u)) >> 16;   // RNE
  return (u16)u;
}
__device__ __forceinline__ float b2f(u16 b) {
  return __uint_as_float(((unsigned)b) << 16);
}

// ---------------------------------------------------------------------------
// setup_k: fused cvtx (blocks 0..2047) + prep (2048..2835)
__global__ __launch_bounds__(256) void setup_k(
    const float* __restrict__ x, u16* __restrict__ xb,
    const float* __restrict__ W_kqv, const float* __restrict__ b_kqv,
    const float* __restrict__ W_att1, const float* __restrict__ b_att1,
    const float* __restrict__ W_out,
    u16* __restrict__ BcatT, float* __restrict__ biascat,
    u16* __restrict__ wa1t, u16* __restrict__ WoutT)
{
  __shared__ float tile[64][65];
  const float inv_sqrt_hd = 0.17677669529663687f;  // 1/sqrt(32)
  int bx = blockIdx.x, t = threadIdx.x;

  if (bx < 2048) {                    // ---- cvtx: x fp32 -> bf16
    int i = bx * 256 + t;
    float4 v = ((const float4*)x)[i];
    ushort4 o;
    o.x = f2b(v.x); o.y = f2b(v.y); o.z = f2b(v.z); o.w = f2b(v.w);
    ((ushort4*)xb)[i] = o;
    return;
  }
  int c = bx - 2048;                  // ---- prep
  int i = t;
  if (c < 768) {
    float v;
    if (c < 256) {
      int h = c >> 5, d2 = c & 31;
      float s = 0.f;
      #pragma unroll
      for (int j = 0; j < 32; ++j)
        s += W_kqv[i*768 + 256 + h*32 + j] * W_att1[j*32 + d2];
      v = s * inv_sqrt_hd;
    } else if (c < 512) {
      int c2 = c - 256; int h = c2 >> 5, d2 = c2 & 31;
      float s = 0.f;
      #pragma unroll
      for (int j = 0; j < 32; ++j)
        s += W_kqv[i*768 + h*32 + j] * W_att1[(32+j)*32 + d2];
      v = s;
    } else {
      v = W_kqv[i*768 + c];
    }
    BcatT[(size_t)c * 256 + i] = f2b(v);
    if (i == 0) {
      float bv;
      if (c < 256) {
        int h = c >> 5, d2 = c & 31;
        float s = 0.f;
        for (int j = 0; j < 32; ++j)
          s += b_kqv[256 + h*32 + j] * W_att1[j*32 + d2];
        bv = s * inv_sqrt_hd;
      } else if (c < 512) {
        int c2 = c - 256; int h = c2 >> 5, d2 = c2 & 31;
        float s = 0.f;
        for (int j = 0; j < 32; ++j)
          s += b_kqv[h*32 + j] * W_att1[(32+j)*32 + d2];
        bv = s + b_att1[c2 & 31];             // fold b_att1 into qW bias
      } else {
        bv = b_kqv[c];
      }
      biascat[c] = bv;
    }
  } else if (c < 772) {
    int idx = (c - 768) * 256 + i;
    int d2 = idx >> 5, j = idx & 31;
    wa1t[idx] = f2b(W_att1[(64 + j) * 32 + d2]);
  } else {
    int b = c - 772;
    int r0 = (b >> 2) * 64, c0 = (b & 3) * 64;
    for (int idx = i; idx < 4096; idx += 256) {
      int r = idx >> 6, cc = idx & 63;
      tile[r][cc] = W_out[(size_t)(r0 + r) * 256 + c0 + cc];
    }
    __syncthreads();
    for (int idx = i; idx < 4096; idx += 256) {
      int cc = idx >> 6, r = idx & 63;
      WoutT[(size_t)(c0 + cc) * 256 + r0 + r] = f2b(tile[r][cc]);
    }
  }
}

// ---------------------------------------------------------------------------
// nodeF[8192][768] bf16 = xb @ BcatT^T + biascat. MFMA 16x16x32.
__global__ __launch_bounds__(256) void gemm_nf_k(const u16* __restrict__ xb,
                                                 const u16* __restrict__ BcatT,
                                                 const float* __restrict__ biascat,
                                                 u16* __restrict__ nodeF) {
  int t = threadIdx.x, lane = t & 63, wid = t >> 6;
  int r0 = (blockIdx.x * 4 + wid) * 32;
  int c0 = blockIdx.y * 32;
  int lr = lane & 15, lk = (lane >> 4) * 8;
  f32x4 acc00 = {0.f,0.f,0.f,0.f}, acc01 = {0.f,0.f,0.f,0.f};
  f32x4 acc10 = {0.f,0.f,0.f,0.f}, acc11 = {0.f,0.f,0.f,0.f};
  for (int k0 = 0; k0 < 256; k0 += 32) {
    bf16x8 a0 = *(const bf16x8*)&xb[(size_t)(r0 + lr) * 256 + k0 + lk];
    bf16x8 a1 = *(const bf16x8*)&xb[(size_t)(r0 + 16 + lr) * 256 + k0 + lk];
    bf16x8 b0 = *(const bf16x8*)&BcatT[(size_t)(c0 + lr) * 256 + k0 + lk];
    bf16x8 b1 = *(const bf16x8*)&BcatT[(size_t)(c0 + 16 + lr) * 256 + k0 + lk];
    acc00 = __builtin_amdgcn_mfma_f32_16x16x32_bf16(a0, b0, acc00, 0, 0, 0);
    acc01 = __builtin_amdgcn_mfma_f32_16x16x32_bf16(a0, b1, acc01, 0, 0, 0);
    acc10 = __builtin_amdgcn_mfma_f32_16x16x32_bf16(a1, b0, acc10, 0, 0, 0);
    acc11 = __builtin_amdgcn_mfma_f32_16x16x32_bf16(a1, b1, acc11, 0, 0, 0);
  }
  float bias0 = biascat[c0 + lr];
  float bias1 = biascat[c0 + 16 + lr];
  int rbase = r0 + (lane >> 4) * 4;
  #pragma unroll
  for (int r = 0; r < 4; ++r) {
    nodeF[(size_t)(rbase + r) * 768 + c0 + lr]           = f2b(acc00[r] + bias0);
    nodeF[(size_t)(rbase + r) * 768 + c0 + 16 + lr]      = f2b(acc01[r] + bias1);
    nodeF[(size_t)(rbase + 16 + r) * 768 + c0 + lr]      = f2b(acc10[r] + bias0);
    nodeF[(size_t)(rbase + 16 + r) * 768 + c0 + 16 + lr] = f2b(acc11[r] + bias1);
  }
}

// ---------------------------------------------------------------------------
// Edge-parallel logits + CSR scatter. 2 slots per wave per iter, LITER iters.
// Grid: NSLOT/(8*LITER) blocks of 256 threads.
__global__ __launch_bounds__(256) void logits_k(
    const int* __restrict__ ei, const int* __restrict__ qm,
    const float* __restrict__ eattr, const u16* __restrict__ nf,
    const u16* __restrict__ wa1t,
    const float* __restrict__ W_edge, const float* __restrict__ b_edge,
    const float* __restrict__ W_att2,
    int* __restrict__ cnt, int* __restrict__ src_csr, float* __restrict__ lg)
{
  // [wid][rslot][row]: rslot 0/1 = kW of e0/e1, 2/3 = qW of e0/e1
  __shared__ __align__(16) u16 kq[4][4][336];

  int t = threadIdx.x, lane = t & 63, wid = t >> 6;

  // per-lane weights in registers (hoisted)
  int h_a = lane & 7, j0 = (lane >> 4) * 8;
  float4 w0a = *(const float4*)&W_edge[h_a*32 + j0];
  float4 w0b = *(const float4*)&W_edge[h_a*32 + j0 + 4];
  float4 w1a = *(const float4*)&W_edge[256 + h_a*32 + j0];
  float4 w1b = *(const float4*)&W_edge[256 + h_a*32 + j0 + 4];
  float4 bba = *(const float4*)&b_edge[h_a*32 + j0];
  float4 bbb = *(const float4*)&b_edge[h_a*32 + j0 + 4];
  bf16x8 b0 = *(const bf16x8*)&wa1t[(lane & 15) * 32 + j0];
  bf16x8 b1 = *(const bf16x8*)&wa1t[512 + (lane & 15) * 32 + j0];
  float w2a = W_att2[lane & 15], w2b = W_att2[16 + (lane & 15)];
  int d2 = lane & 15;
  int rslot = lane >> 4, re = rslot & 1, rtype = rslot >> 1;

  for (int it = 0; it < LITER; ++it) {
    int s0 = (blockIdx.x * LITER + it) * 8 + wid * 2;

    // ---- decode this lane's row-slot edge (slot = s0 + re)
    int slot = s0 + re;
    int src, dst, validL = 1;
    if (slot < E_RAW) {
      validL = (qm[slot] == 0);
      src = ei[slot]; dst = ei[E_RAW + slot];
    } else if (slot < 2*E_RAW) {
      int e = slot - E_RAW;
      src = ei[E_RAW + e]; dst = ei[e];
    } else {
      int nn = slot - 2*E_RAW;
      src = nn; dst = nn;
    }

    // ---- stage row (kW or qW) into LDS: 16 lanes x 32B per row
    int node = rtype ? dst : src;
    const u16* rp = &nf[(size_t)node * 768 + (rtype ? 256 : 0) + (lane & 15) * 16];
    bf16x8 rv0 = *(const bf16x8*)rp;
    bf16x8 rv1 = *(const bf16x8*)(rp + 8);

    // ---- broadcast edge metadata
    int valid0 = __shfl(validL, 0),  valid1 = __shfl(validL, 16);
    int dst0   = __shfl(dst, 32),    dst1   = __shfl(dst, 48);
    int src0v  = __shfl(src, 0),     src1v  = __shfl(src, 16);

    // ---- CSR position (overlapped with compute below)
    int myPos = 0;
    if (lane == 0 && valid0) myPos = atomicAdd(&cnt[dst0], 1);
    if (lane == 1 && valid1) myPos = atomicAdd(&cnt[dst1], 1);
    int pos0 = __shfl(myPos, 0), pos1 = __shfl(myPos, 1);

    // ---- edge features for A-operand (row = eoff*8 + h_a)
    int slot_ea = s0 + ((lane >> 3) & 1);
    float a0 = 0.f, a1 = 0.f;
    if (slot_ea < 2*E_RAW) {
      int em = slot_ea < E_RAW ? slot_ea : slot_ea - E_RAW;
      float2 ld = *(const float2*)&eattr[2*em];
      a0 = ld.x; a1 = ld.y;
    }
    bf16x8 af;
    { float v;
      v = fmaf(a0, w0a.x, fmaf(a1, w1a.x, bba.x)); af[0] = (short)f2b(fmaxf(v, 0.f));
      v = fmaf(a0, w0a.y, fmaf(a1, w1a.y, bba.y)); af[1] = (short)f2b(fmaxf(v, 0.f));
      v = fmaf(a0, w0a.z, fmaf(a1, w1a.z, bba.z)); af[2] = (short)f2b(fmaxf(v, 0.f));
      v = fmaf(a0, w0a.w, fmaf(a1, w1a.w, bba.w)); af[3] = (short)f2b(fmaxf(v, 0.f));
      v = fmaf(a0, w0b.x, fmaf(a1, w1b.x, bbb.x)); af[4] = (short)f2b(fmaxf(v, 0.f));
      v = fmaf(a0, w0b.y, fmaf(a1, w1b.y, bbb.y)); af[5] = (short)f2b(fmaxf(v, 0.f));
      v = fmaf(a0, w0b.z, fmaf(a1, w1b.z, bbb.z)); af[6] = (short)f2b(fmaxf(v, 0.f));
      v = fmaf(a0, w0b.w, fmaf(a1, w1b.w, bbb.w)); af[7] = (short)f2b(fmaxf(v, 0.f));
    }

    // ---- LDS stores (chunked d2-octets, 40-stride rows)
    {
      int idx0 = (lane & 15) * 2;
      *(bf16x8*)&kq[wid][rslot][(idx0 >> 2) * 40 + (idx0 & 3) * 8] = rv0;
      int idx1 = idx0 + 1;
      *(bf16x8*)&kq[wid][rslot][(idx1 >> 2) * 40 + (idx1 & 3) * 8] = rv1;
    }
    __builtin_amdgcn_wave_barrier();

    // ---- MFMA: 16 rows (2 edges x 8 heads) x 32 d2, K=32
    f32x4 acc0 = {0.f,0.f,0.f,0.f}, acc1 = {0.f,0.f,0.f,0.f};
    acc0 = __builtin_amdgcn_mfma_f32_16x16x32_bf16(af, b0, acc0, 0, 0, 0);
    acc1 = __builtin_amdgcn_mfma_f32_16x16x32_bf16(af, b1, acc1, 0, 0, 0);

    // ---- epilogue: add kW+qW, relu, dot W_att2, reduce over d2
    float vvs[4];
    #pragma unroll
    for (int r = 0; r < 4; ++r) {
      int grr = (lane >> 4) * 4 + r;
      int e = grr >> 3, hh = grr & 7;
      float kv0 = b2f(kq[wid][e][hh * 40 + d2]);
      float kv1 = b2f(kq[wid][e][hh * 40 + 16 + d2]);
      float qv0 = b2f(kq[wid][2 + e][hh * 40 + d2]);
      float qv1 = b2f(kq[wid][2 + e][hh * 40 + 16 + d2]);
      float p0 = acc0[r] + kv0 + qv0;
      float p1 = acc1[r] + kv1 + qv1;
      float vv = fmaxf(p0, 0.f) * w2a + fmaxf(p1, 0.f) * w2b;
      vv += __shfl_xor(vv, 1); vv += __shfl_xor(vv, 2);
      vv += __shfl_xor(vv, 4); vv += __shfl_xor(vv, 8);
      vvs[r] = vv;
    }

    // ---- scatter results
    if (lane == 0 && valid0 && pos0 < DEGCAP) src_csr[dst0 * DEGCAP + pos0] = src0v;
    if (lane == 1 && valid1 && pos1 < DEGCAP) src_csr[dst1 * DEGCAP + pos1] = src1v;
    if (d2 == 0) {
      #pragma unroll
      for (int r = 0; r < 4; ++r) {
        int grr = (lane >> 4) * 4 + r;
        int e = grr >> 3, hh = grr & 7;
        int vd = e ? valid1 : valid0;
        int pp = e ? pos1 : pos0;
        int dd = e ? dst1 : dst0;
        if (vd && pp < DEGCAP)
          lg[((size_t)dd * DEGCAP + pp) * 8 + hh] = vvs[r];
      }
    }
    __builtin_amdgcn_wave_barrier();
  }
}

// ---------------------------------------------------------------------------
// Per-node segment softmax + alpha-weighted V aggregation. Wave per node.
__global__ __launch_bounds__(256) void aggr_k(const int* __restrict__ cnt,
                                              const int* __restrict__ src_csr,
                                              const float* __restrict__ lg,
                                              const u16* __restrict__ nf,
                                              u16* __restrict__ aggb) {
  int t = threadIdx.x, lane = t & 63, wid = t >> 6;
  int n = blockIdx.x * 4 + wid;
  int deg = cnt[n]; if (deg > DEGCAP) deg = DEGCAP;
  const float* lgn = lg + (size_t)n * DEGCAP * 8;

  // softmax stats: lanes (i = lane>>3, h = lane&7)
  float m = -3.4e38f, s = 0.f;
  for (int i = lane >> 3; i < deg; i += 8) {
    float val = lgn[i * 8 + (lane & 7)];
    float mn = fmaxf(m, val);
    s = s * __expf(m - mn) + __expf(val - mn);
    m = mn;
  }
  #pragma unroll
  for (int msk = 8; msk <= 32; msk <<= 1) {
    float mo = __shfl_xor(m, msk), so = __shfl_xor(s, msk);
    float mn = fmaxf(m, mo);
    s = s * __expf(m - mn) + so * __expf(mo - mn);
    m = mn;
  }
  float sinv = 1.f / (s + 1e-16f);
  int head = lane >> 3;
  float mh = __shfl(m, head);         // stats for head = lane>>3
  float sh = __shfl(sinv, head);

  // aggregation: lane owns dims lane*4 .. lane*4+3 (head = lane>>3)
  float ac0 = 0.f, ac1 = 0.f, ac2 = 0.f, ac3 = 0.f;
  const u16* vb = nf + 512 + lane * 4;
  for (int i = 0; i < deg; ++i) {
    int srcv = src_csr[n * DEGCAP + i];
    float a = __expf(lgn[i * 8 + head] - mh) * sh;
    bf16x4 v = *(const bf16x4*)&vb[(size_t)srcv * 768];
    ac0 = fmaf(a, b2f((u16)v[0]), ac0);
    ac1 = fmaf(a, b2f((u16)v[1]), ac1);
    ac2 = fmaf(a, b2f((u16)v[2]), ac2);
    ac3 = fmaf(a, b2f((u16)v[3]), ac3);
  }
  ushort4 o; o.x = f2b(ac0); o.y = f2b(ac1); o.z = f2b(ac2); o.w = f2b(ac3);
  *(ushort4*)&aggb[(size_t)n * 256 + lane * 4] = o;
}

// ---------------------------------------------------------------------------
// out = aggb @ WoutT^T + x + deg*b_out (fp32 out), fused BN partial sums.
__global__ __launch_bounds__(256) void gemmout_k(const u16* __restrict__ aggb,
                                                 const u16* __restrict__ WoutT,
                                                 const float* __restrict__ x,
                                                 const int* __restrict__ cnt,
                                                 const float* __restrict__ b_out,
                                                 float* __restrict__ out,
                                                 float* __restrict__ bnsum,
                                                 float* __restrict__ bnsq) {
  int t = threadIdx.x, lane = t & 63, wid = t >> 6;
  int r0 = (blockIdx.x * 4 + wid) * 32;
  int c0 = blockIdx.y * 32;
  int lr = lane & 15, lk = (lane >> 4) * 8;
  f32x4 acc00 = {0.f,0.f,0.f,0.f}, acc01 = {0.f,0.f,0.f,0.f};
  f32x4 acc10 = {0.f,0.f,0.f,0.f}, acc11 = {0.f,0.f,0.f,0.f};
  for (int k0 = 0; k0 < 256; k0 += 32) {
    bf16x8 a0 = *(const bf16x8*)&aggb[(size_t)(r0 + lr) * 256 + k0 + lk];
    bf16x8 a1 = *(const bf16x8*)&aggb[(size_t)(r0 + 16 + lr) * 256 + k0 + lk];
    bf16x8 b0 = *(const bf16x8*)&WoutT[(size_t)(c0 + lr) * 256 + k0 + lk];
    bf16x8 b1 = *(const bf16x8*)&WoutT[(size_t)(c0 + 16 + lr) * 256 + k0 + lk];
    acc00 = __builtin_amdgcn_mfma_f32_16x16x32_bf16(a0, b0, acc00, 0, 0, 0);
    acc01 = __builtin_amdgcn_mfma_f32_16x16x32_bf16(a0, b1, acc01, 0, 0, 0);
    acc10 = __builtin_amdgcn_mfma_f32_16x16x32_bf16(a1, b0, acc10, 0, 0, 0);
    acc11 = __builtin_amdgcn_mfma_f32_16x16x32_bf16(a1, b1, acc11, 0, 0, 0);
  }
  int colA = c0 + lr, colB = c0 + 16 + lr;
  float bA = b_out[colA], bB = b_out[colB];
  int rbase = r0 + (lane >> 4) * 4;
  float sA = 0.f, qA = 0.f, sB = 0.f, qB = 0.f;
  #pragma unroll
  for (int r = 0; r < 4; ++r) {
    int rowA = rbase + r, rowB = rbase + 16 + r;
    float degA = (float)cnt[rowA], degB = (float)cnt[rowB];
    float v00 = acc00[r] + x[(size_t)rowA * 256 + colA] + degA * bA;
    float v01 = acc01[r] + x[(size_t)rowA * 256 + colB] + degA * bB;
    float v10 = acc10[r] + x[(size_t)rowB * 256 + colA] + degB * bA;
    float v11 = acc11[r] + x[(size_t)rowB * 256 + colB] + degB * bB;
    out[(size_t)rowA * 256 + colA] = v00;
    out[(size_t)rowA * 256 + colB] = v01;
    out[(size_t)rowB * 256 + colA] = v10;
    out[(size_t)rowB * 256 + colB] = v11;
    sA += v00 + v10; qA += v00*v00 + v10*v10;
    sB += v01 + v11; qB += v01*v01 + v11*v11;
  }
  #pragma unroll
  for (int msk = 16; msk <= 32; msk <<= 1) {
    sA += __shfl_xor(sA, msk); qA += __shfl_xor(qA, msk);
    sB += __shfl_xor(sB, msk); qB += __shfl_xor(qB, msk);
  }
  if (lane < 16) {
    atomicAdd(&bnsum[colA], sA); atomicAdd(&bnsq[colA], qA);
    atomicAdd(&bnsum[colB], sB); atomicAdd(&bnsq[colB], qB);
  }
}

// ---------------------------------------------------------------------------
__global__ __launch_bounds__(256) void bnapply_k(float* __restrict__ out,
                                                 const float* __restrict__ bnsum,
                                                 const float* __restrict__ bnsq,
                                                 const float* __restrict__ gamma,
                                                 const float* __restrict__ beta) {
  int t = threadIdx.x;
  int r = blockIdx.x;
  float mu = bnsum[t] * (1.f / 8192.f);
  float var = bnsq[t] * (1.f / 8192.f) - mu*mu;
  float inv = rsqrtf(var + 1e-5f);
  size_t idx = (size_t)r*256 + t;
  out[idx] = (out[idx] - mu) * inv * gamma[t] + beta[t];
}

// ---------------------------------------------------------------------------
extern "C" void kernel_launch(void* const* d_in, const int* in_sizes, int n_in,
                              void* d_out, int out_size, void* d_ws, size_t ws_size,
                              hipStream_t stream) {
  (void)in_sizes; (void)n_in; (void)out_size; (void)ws_size;
  const float* x      = (const float*)d_in[0];
  const int*   ei     = (const int*)d_in[1];
  const float* eattr  = (const float*)d_in[2];
  const int*   qm     = (const int*)d_in[3];
  const float* W_kqv  = (const float*)d_in[5];
  const float* b_kqv  = (const float*)d_in[6];
  const float* W_edge = (const float*)d_in[7];
  const float* b_edge = (const float*)d_in[8];
  const float* W_att1 = (const float*)d_in[9];
  const float* b_att1 = (const float*)d_in[10];
  const float* W_att2 = (const float*)d_in[11];
  // b_att2 cancels in softmax
  const float* W_out  = (const float*)d_in[13];
  const float* b_out  = (const float*)d_in[14];
  const float* gamma  = (const float*)d_in[15];
  const float* beta   = (const float*)d_in[16];
  float* out = (float*)d_out;

  // workspace carve-up (~34 MB)
  char* w = (char*)d_ws;
  u16*    xb      = (u16*)w;     w += (size_t)N_NODES*256*2;
  u16*    BcatT   = (u16*)w;     w += (size_t)768*256*2;
  u16*    wa1t    = (u16*)w;     w += 1024*2;
  u16*    WoutT   = (u16*)w;     w += (size_t)256*256*2;
  u16*    nodeFb  = (u16*)w;     w += (size_t)N_NODES*768*2;
  float*  biascat = (float*)w;   w += 768*4;
  u16*    aggb    = (u16*)w;     w += (size_t)N_NODES*256*2;
  int*    cnt     = (int*)w;     w += N_NODES*4;
  float*  bnsum   = (float*)w;   w += 256*4;
  float*  bnsq    = (float*)w;   w += 256*4;
  int*    src_csr = (int*)w;     w += (size_t)N_NODES*DEGCAP*4;
  float*  lg      = (float*)w;   w += (size_t)N_NODES*DEGCAP*8*4;

  // zero: cnt + bnsum + bnsq (contiguous)
  hipMemsetAsync(cnt, 0, (size_t)(N_NODES + 512) * sizeof(int), stream);

  setup_k<<<2836, 256, 0, stream>>>(x, xb, W_kqv, b_kqv, W_att1, b_att1, W_out,
                                    BcatT, biascat, wa1t, WoutT);

  gemm_nf_k<<<dim3(N_NODES/128, 768/32), 256, 0, stream>>>(xb, BcatT, biascat, nodeFb);

  logits_k<<<NSLOT/(8*LITER), 256, 0, stream>>>(ei, qm, eattr, nodeFb, wa1t,
                                                W_edge, b_edge, W_att2,
                                                cnt, src_csr, lg);

  aggr_k<<<N_NODES/4, 256, 0, stream>>>(cnt, src_csr, lg, nodeFb, aggb);

  gemmout_k<<<dim3(N_NODES/128, 256/32), 256, 0, stream>>>(
      aggb, WoutT, x, cnt, b_out, out, bnsum, bnsq);

  bnapply_k<<<N_NODES, 256, 0, stream>>>(out, bnsum, bnsq, gamma, beta);
}

// Round 6
// 109.877 us; speedup vs baseline: 1.3088x; 1.3088x over previous
//
#include <hip/hip_runtime.h>

#define N_NODES 8192
#define E_RAW   65536
#define NSLOT   (2*E_RAW + N_NODES)   // 139264 slots: [support E][flipped E][self-loops N]
#define DEGCAP  48                    // max deg ~36 (binomial, 8-sigma safe)
#define L_ITER  4

typedef __attribute__((ext_vector_type(8)))  short bf16x8;
typedef __attribute__((ext_vector_type(4)))  short bf16x4;
typedef __attribute__((ext_vector_type(4)))  float f32x4;
typedef __attribute__((ext_vector_type(16))) float f32x16;
typedef unsigned short u16;

__device__ __forceinline__ u16 f2b(float f) {
  unsigned u = __float_as_uint(f);
  u = (u + 0x7FFFu + ((u >> 16) & 1u)) >> 16;   // RNE
  return (u16)u;
}
__device__ __forceinline__ float b2f(u16 b) {
  return __uint_as_float(((unsigned)b) << 16);
}

// ---------------------------------------------------------------------------
// setup_k: cvtx (0..2047) + prep (2048..2835) + beW (2836) + scatter (2837..)
__global__ __launch_bounds__(256) void setup_k(
    const float* __restrict__ x, u16* __restrict__ xb,
    const float* __restrict__ W_kqv, const float* __restrict__ b_kqv,
    const float* __restrict__ W_att1, const float* __restrict__ b_att1,
    const float* __restrict__ W_edge, const float* __restrict__ b_edge,
    const float* __restrict__ W_out,
    u16* __restrict__ BcatT, float* __restrict__ biascat,
    u16* __restrict__ wa1t, u16* __restrict__ WoutT, float* __restrict__ beW,
    const int* __restrict__ ei, const int* __restrict__ qm,
    int* __restrict__ cnt, int* __restrict__ csr)
{
  __shared__ float tile[64][65];
  const float inv_sqrt_hd = 0.17677669529663687f;  // 1/sqrt(32)
  int bx = blockIdx.x, t = threadIdx.x;

  if (bx < 2048) {                    // ---- cvtx
    int i = bx * 256 + t;
    float4 v = ((const float4*)x)[i];
    ushort4 o;
    o.x = f2b(v.x); o.y = f2b(v.y); o.z = f2b(v.z); o.w = f2b(v.w);
    ((ushort4*)xb)[i] = o;
    return;
  }
  if (bx < 2836) {                    // ---- prep
    int c = bx - 2048;
    int i = t;
    if (c < 768) {
      float v;
      if (c < 256) {
        int h = c >> 5, d2 = c & 31;
        float s = 0.f;
        #pragma unroll
        for (int j = 0; j < 32; ++j)
          s += W_kqv[i*768 + 256 + h*32 + j] * W_att1[j*32 + d2];
        v = s * inv_sqrt_hd;
      } else if (c < 512) {
        int c2 = c - 256; int h = c2 >> 5, d2 = c2 & 31;
        float s = 0.f;
        #pragma unroll
        for (int j = 0; j < 32; ++j)
          s += W_kqv[i*768 + h*32 + j] * W_att1[(32+j)*32 + d2];
        v = s;
      } else {
        v = W_kqv[i*768 + c];
      }
      BcatT[(size_t)c * 256 + i] = f2b(v);
      if (i == 0) {
        float bv;
        if (c < 256) {
          int h = c >> 5, d2 = c & 31;
          float s = 0.f;
          for (int j = 0; j < 32; ++j)
            s += b_kqv[256 + h*32 + j] * W_att1[j*32 + d2];
          bv = s * inv_sqrt_hd;
        } else if (c < 512) {
          int c2 = c - 256; int h = c2 >> 5, d2 = c2 & 31;
          float s = 0.f;
          for (int j = 0; j < 32; ++j)
            s += b_kqv[h*32 + j] * W_att1[(32+j)*32 + d2];
          bv = s + b_att1[c2 & 31];             // fold b_att1 into qW bias
        } else {
          bv = b_kqv[c];
        }
        biascat[c] = bv;
      }
    } else if (c < 772) {
      int idx = (c - 768) * 256 + i;
      int d2 = idx >> 5, j = idx & 31;
      wa1t[idx] = f2b(W_att1[(64 + j) * 32 + d2]);
    } else {
      int b = c - 772;
      int r0 = (b >> 2) * 64, c0 = (b & 3) * 64;
      for (int idx = i; idx < 4096; idx += 256) {
        int r = idx >> 6, cc = idx & 63;
        tile[r][cc] = W_out[(size_t)(r0 + r) * 256 + c0 + cc];
      }
      __syncthreads();
      for (int idx = i; idx < 4096; idx += 256) {
        int cc = idx >> 6, r = idx & 63;
        WoutT[(size_t)(c0 + cc) * 256 + r0 + r] = f2b(tile[r][cc]);
      }
    }
    return;
  }
  if (bx == 2836) {                   // ---- beW[h][d2] = relu(b_edge[h,:]) @ W1b
    int h = t >> 5, d2 = t & 31;
    float s = 0.f;
    #pragma unroll
    for (int f = 0; f < 32; ++f)
      s += fmaxf(b_edge[h*32 + f], 0.f) * W_att1[(64 + f)*32 + d2];
    beW[h*32 + d2] = s;
    return;
  }
  // ---- scatter: packed CSR (slot<<13 | src)
  int slot = (bx - 2837) * 256 + t;
  if (slot >= NSLOT) return;
  int src, dst;
  if (slot < E_RAW) {
    if (qm[slot] != 0) return;
    src = ei[slot]; dst = ei[E_RAW + slot];
  } else if (slot < 2*E_RAW) {
    int e = slot - E_RAW;
    src = ei[E_RAW + e]; dst = ei[e];
  } else {
    int n = slot - 2*E_RAW;
    src = n; dst = n;
  }
  int pos = atomicAdd(&cnt[dst], 1);
  if (pos < DEGCAP) csr[dst*DEGCAP + pos] = (slot << 13) | src;
}

// ---------------------------------------------------------------------------
// nodeF[8192][768] bf16 = xb @ BcatT^T + biascat. MFMA 16x16x32.
// grid (24 col-tiles fastest, 64 row-groups) for L2 A-panel reuse.
__global__ __launch_bounds__(256) void gemm_nf_k(const u16* __restrict__ xb,
                                                 const u16* __restrict__ BcatT,
                                                 const float* __restrict__ biascat,
                                                 u16* __restrict__ nodeF) {
  int t = threadIdx.x, lane = t & 63, wid = t >> 6;
  int r0 = (blockIdx.y * 4 + wid) * 32;
  int c0 = blockIdx.x * 32;
  int lr = lane & 15, lk = (lane >> 4) * 8;
  f32x4 acc00 = {0.f,0.f,0.f,0.f}, acc01 = {0.f,0.f,0.f,0.f};
  f32x4 acc10 = {0.f,0.f,0.f,0.f}, acc11 = {0.f,0.f,0.f,0.f};
  for (int k0 = 0; k0 < 256; k0 += 32) {
    bf16x8 a0 = *(const bf16x8*)&xb[(size_t)(r0 + lr) * 256 + k0 + lk];
    bf16x8 a1 = *(const bf16x8*)&xb[(size_t)(r0 + 16 + lr) * 256 + k0 + lk];
    bf16x8 b0 = *(const bf16x8*)&BcatT[(size_t)(c0 + lr) * 256 + k0 + lk];
    bf16x8 b1 = *(const bf16x8*)&BcatT[(size_t)(c0 + 16 + lr) * 256 + k0 + lk];
    acc00 = __builtin_amdgcn_mfma_f32_16x16x32_bf16(a0, b0, acc00, 0, 0, 0);
    acc01 = __builtin_amdgcn_mfma_f32_16x16x32_bf16(a0, b1, acc01, 0, 0, 0);
    acc10 = __builtin_amdgcn_mfma_f32_16x16x32_bf16(a1, b0, acc10, 0, 0, 0);
    acc11 = __builtin_amdgcn_mfma_f32_16x16x32_bf16(a1, b1, acc11, 0, 0, 0);
  }
  float bias0 = biascat[c0 + lr];
  float bias1 = biascat[c0 + 16 + lr];
  int rbase = r0 + (lane >> 4) * 4;
  #pragma unroll
  for (int r = 0; r < 4; ++r) {
    nodeF[(size_t)(rbase + r) * 768 + c0 + lr]           = f2b(acc00[r] + bias0);
    nodeF[(size_t)(rbase + r) * 768 + c0 + 16 + lr]      = f2b(acc01[r] + bias1);
    nodeF[(size_t)(rbase + 16 + r) * 768 + c0 + lr]      = f2b(acc10[r] + bias0);
    nodeF[(size_t)(rbase + 16 + r) * 768 + c0 + 16 + lr] = f2b(acc11[r] + bias1);
  }
}

// ---------------------------------------------------------------------------
// logits for all slots, dense by slot. Main blocks (0..1023): 4 raw edges per
// wave-iter -> support + flipped slots share one EF-MFMA. Tail blocks
// (1024..1151): self-loop slots, no MFMA (beW precomputed).
// C-layout of 32x32x16: col = lane&31 = (e*8+h); lane holds 16 d2 values.
__global__ __launch_bounds__(256) void logits_k(
    const int* __restrict__ ei, const int* __restrict__ qm,
    const float* __restrict__ eattr, const u16* __restrict__ nf,
    const u16* __restrict__ wa1t,
    const float* __restrict__ W_edge, const float* __restrict__ b_edge,
    const float* __restrict__ W_att2, const float* __restrict__ beW,
    float* __restrict__ lgd)
{
  __shared__ __align__(16) u16 kqls[4][16][8][40];   // [wid][row][h][32+8 pad]

  int bx = blockIdx.x, t = threadIdx.x, lane = t & 63, wid = t >> 6;
  int col = lane & 31;
  int e = col >> 3, h = col & 7, hi = lane >> 5;

  // per-lane W_att2 for its 16 d2 rows
  float w2r[16];
  #pragma unroll
  for (int r = 0; r < 16; ++r)
    w2r[r] = W_att2[(r & 3) + 8*(r >> 2) + 4*hi];

  if (bx < 1024) {
    // per-lane edge-MLP coefficients: head h, f = hi*8+i (lo) / 16+hi*8+i (hi)
    float ce0[16], ce1[16], cbe[16];
    #pragma unroll
    for (int i = 0; i < 8; ++i) {
      int fA = hi*8 + i, fB = 16 + hi*8 + i;
      ce0[i]   = W_edge[h*32 + fA];       ce0[8+i] = W_edge[h*32 + fB];
      ce1[i]   = W_edge[256 + h*32 + fA]; ce1[8+i] = W_edge[256 + h*32 + fB];
      cbe[i]   = b_edge[h*32 + fA];       cbe[8+i] = b_edge[h*32 + fB];
    }
    // constant A-frags: A[d2=lane&31][f = hi*8+i (+16)]
    bf16x8 af0 = *(const bf16x8*)&wa1t[(lane & 31)*32 + hi*8];
    bf16x8 af1 = *(const bf16x8*)&wa1t[(lane & 31)*32 + 16 + hi*8];

    for (int it = 0; it < L_ITER; ++it) {
      int er0 = ((bx * L_ITER + it) * 4 + wid) * 4;
      int er = er0 + e;
      int eqm = qm[er];
      float2 ea = *(const float2*)&eattr[2*er];

      // stage 16 rows: 0-3 kW[src], 4-7 kW[dst], 8-11 qW[src], 12-15 qW[dst]
      #pragma unroll
      for (int m = 0; m < 8; ++m) {
        int flat = m*64 + lane;
        int ri = flat >> 5, chunk = flat & 31;
        int ee = ri & 3, ty = ri >> 2;
        int erow = er0 + ee;
        int node = (ty & 1) ? ei[E_RAW + erow] : ei[erow];
        int koff = (ty >> 1) ? 256 : 0;
        bf16x8 v = *(const bf16x8*)&nf[(size_t)node*768 + koff + chunk*8];
        *(bf16x8*)&kqls[wid][ri][chunk >> 2][(chunk & 3)*8] = v;
      }

      // B-frag: ef[f][col] for this lane's (e,h), f-halves per hi
      bf16x8 bf0, bf1;
      #pragma unroll
      for (int i = 0; i < 8; ++i) {
        float v0 = fmaf(ea.x, ce0[i],   fmaf(ea.y, ce1[i],   cbe[i]));
        float v1 = fmaf(ea.x, ce0[8+i], fmaf(ea.y, ce1[8+i], cbe[8+i]));
        bf0[i] = (short)f2b(fmaxf(v0, 0.f));
        bf1[i] = (short)f2b(fmaxf(v1, 0.f));
      }
      f32x16 acc = {};
      acc = __builtin_amdgcn_mfma_f32_32x32x16_bf16(af0, bf0, acc, 0, 0, 0);
      acc = __builtin_amdgcn_mfma_f32_32x32x16_bf16(af1, bf1, acc, 0, 0, 0);

      __builtin_amdgcn_wave_barrier();

      // epilogue: both directions. support: k_src(e) + q_dst(12+e);
      //                             flipped: k_dst(4+e) + q_src(8+e)
      float lg0 = 0.f, lg1 = 0.f;
      #pragma unroll
      for (int q = 0; q < 4; ++q) {
        int off = q*8 + 4*hi;
        bf16x4 k0 = *(const bf16x4*)&kqls[wid][e][h][off];
        bf16x4 q0 = *(const bf16x4*)&kqls[wid][12 + e][h][off];
        bf16x4 k1 = *(const bf16x4*)&kqls[wid][4 + e][h][off];
        bf16x4 q1 = *(const bf16x4*)&kqls[wid][8 + e][h][off];
        #pragma unroll
        for (int j = 0; j < 4; ++j) {
          int r = q*4 + j;
          float efw = acc[r];
          float p0 = efw + b2f((u16)k0[j]) + b2f((u16)q0[j]);
          float p1 = efw + b2f((u16)k1[j]) + b2f((u16)q1[j]);
          lg0 = fmaf(fmaxf(p0, 0.f), w2r[r], lg0);
          lg1 = fmaf(fmaxf(p1, 0.f), w2r[r], lg1);
        }
      }
      lg0 += __shfl_xor(lg0, 32);
      lg1 += __shfl_xor(lg1, 32);
      if (hi == 0) {
        if (eqm == 0) lgd[(size_t)er*8 + h] = lg0;          // support slot
        lgd[(size_t)(E_RAW + er)*8 + h] = lg1;              // flipped slot
      }
      __builtin_amdgcn_wave_barrier();
    }
  } else {
    // ---- self-loop slots: logit = sum relu(k + q + beW)·w2
    float bew[16];
    #pragma unroll
    for (int r = 0; r < 16; ++r)
      bew[r] = beW[h*32 + (r & 3) + 8*(r >> 2) + 4*hi];

    for (int it = 0; it < L_ITER; ++it) {
      int n0 = (((bx - 1024) * L_ITER + it) * 4 + wid) * 4;
      int nn = n0 + e;
      #pragma unroll
      for (int m = 0; m < 4; ++m) {
        int flat = m*64 + lane;
        int ri = flat >> 5, chunk = flat & 31;   // rows 0-3 kW, 4-7 qW
        int ee = ri & 3, ty = ri >> 2;
        int node = n0 + ee;
        bf16x8 v = *(const bf16x8*)&nf[(size_t)node*768 + (ty ? 256 : 0) + chunk*8];
        *(bf16x8*)&kqls[wid][ri][chunk >> 2][(chunk & 3)*8] = v;
      }
      __builtin_amdgcn_wave_barrier();
      float lg0 = 0.f;
      #pragma unroll
      for (int q = 0; q < 4; ++q) {
        int off = q*8 + 4*hi;
        bf16x4 k0 = *(const bf16x4*)&kqls[wid][e][h][off];
        bf16x4 q0 = *(const bf16x4*)&kqls[wid][4 + e][h][off];
        #pragma unroll
        for (int j = 0; j < 4; ++j) {
          int r = q*4 + j;
          float p = bew[r] + b2f((u16)k0[j]) + b2f((u16)q0[j]);
          lg0 = fmaf(fmaxf(p, 0.f), w2r[r], lg0);
        }
      }
      lg0 += __shfl_xor(lg0, 32);
      if (hi == 0) lgd[(size_t)(2*E_RAW + nn)*8 + h] = lg0;
      __builtin_amdgcn_wave_barrier();
    }
  }
}

// ---------------------------------------------------------------------------
// Per-node segment softmax + alpha-weighted V aggregation. Wave per node.
__global__ __launch_bounds__(256) void aggr_k(const int* __restrict__ cnt,
                                              const int* __restrict__ csr,
                                              const float* __restrict__ lgd,
                                              const u16* __restrict__ nf,
                                              u16* __restrict__ aggb) {
  int t = threadIdx.x, lane = t & 63, wid = t >> 6;
  int n = blockIdx.x * 4 + wid;
  int deg = cnt[n]; if (deg > DEGCAP) deg = DEGCAP;

  // softmax stats: lane = (i = lane>>3 strided 8, h = lane&7)
  float m = -3.4e38f, s = 0.f;
  for (int i = lane >> 3; i < deg; i += 8) {
    int pk = csr[n*DEGCAP + i];
    float val = lgd[(size_t)((unsigned)pk >> 13)*8 + (lane & 7)];
    float mn = fmaxf(m, val);
    s = s * __expf(m - mn) + __expf(val - mn);
    m = mn;
  }
  #pragma unroll
  for (int msk = 8; msk <= 32; msk <<= 1) {
    float mo = __shfl_xor(m, msk), so = __shfl_xor(s, msk);
    float mn = fmaxf(m, mo);
    s = s * __expf(m - mn) + so * __expf(mo - mn);
    m = mn;
  }
  float sinv = 1.f / (s + 1e-16f);
  int head = lane >> 3;
  float mh = __shfl(m, head);
  float sh = __shfl(sinv, head);

  // aggregation: lane owns dims lane*4..+3 of head lane>>3
  float ac0 = 0.f, ac1 = 0.f, ac2 = 0.f, ac3 = 0.f;
  const u16* vb = nf + 512 + lane * 4;
  #pragma unroll 2
  for (int i = 0; i < deg; ++i) {
    int pk = csr[n*DEGCAP + i];
    int slot = (unsigned)pk >> 13, srcv = pk & 8191;
    float a = __expf(lgd[(size_t)slot*8 + head] - mh) * sh;
    bf16x4 v = *(const bf16x4*)&vb[(size_t)srcv * 768];
    ac0 = fmaf(a, b2f((u16)v[0]), ac0);
    ac1 = fmaf(a, b2f((u16)v[1]), ac1);
    ac2 = fmaf(a, b2f((u16)v[2]), ac2);
    ac3 = fmaf(a, b2f((u16)v[3]), ac3);
  }
  ushort4 o; o.x = f2b(ac0); o.y = f2b(ac1); o.z = f2b(ac2); o.w = f2b(ac3);
  *(ushort4*)&aggb[(size_t)n * 256 + lane * 4] = o;
}

// ---------------------------------------------------------------------------
// out = aggb @ WoutT^T + x + deg*b_out (fp32 out), fused BN partial sums.
__global__ __launch_bounds__(256) void gemmout_k(const u16* __restrict__ aggb,
                                                 const u16* __restrict__ WoutT,
                                                 const float* __restrict__ x,
                                                 const int* __restrict__ cnt,
                                                 const float* __restrict__ b_out,
                                                 float* __restrict__ out,
                                                 float* __restrict__ bnsum,
                                                 float* __restrict__ bnsq) {
  int t = threadIdx.x, lane = t & 63, wid = t >> 6;
  int r0 = (blockIdx.y * 4 + wid) * 32;
  int c0 = blockIdx.x * 32;
  int lr = lane & 15, lk = (lane >> 4) * 8;
  f32x4 acc00 = {0.f,0.f,0.f,0.f}, acc01 = {0.f,0.f,0.f,0.f};
  f32x4 acc10 = {0.f,0.f,0.f,0.f}, acc11 = {0.f,0.f,0.f,0.f};
  for (int k0 = 0; k0 < 256; k0 += 32) {
    bf16x8 a0 = *(const bf16x8*)&aggb[(size_t)(r0 + lr) * 256 + k0 + lk];
    bf16x8 a1 = *(const bf16x8*)&aggb[(size_t)(r0 + 16 + lr) * 256 + k0 + lk];
    bf16x8 b0 = *(const bf16x8*)&WoutT[(size_t)(c0 + lr) * 256 + k0 + lk];
    bf16x8 b1 = *(const bf16x8*)&WoutT[(size_t)(c0 + 16 + lr) * 256 + k0 + lk];
    acc00 = __builtin_amdgcn_mfma_f32_16x16x32_bf16(a0, b0, acc00, 0, 0, 0);
    acc01 = __builtin_amdgcn_mfma_f32_16x16x32_bf16(a0, b1, acc01, 0, 0, 0);
    acc10 = __builtin_amdgcn_mfma_f32_16x16x32_bf16(a1, b0, acc10, 0, 0, 0);
    acc11 = __builtin_amdgcn_mfma_f32_16x16x32_bf16(a1, b1, acc11, 0, 0, 0);
  }
  int colA = c0 + lr, colB = c0 + 16 + lr;
  float bA = b_out[colA], bB = b_out[colB];
  int rbase = r0 + (lane >> 4) * 4;
  float sA = 0.f, qA = 0.f, sB = 0.f, qB = 0.f;
  #pragma unroll
  for (int r = 0; r < 4; ++r) {
    int rowA = rbase + r, rowB = rbase + 16 + r;
    float degA = (float)cnt[rowA], degB = (float)cnt[rowB];
    float v00 = acc00[r] + x[(size_t)rowA * 256 + colA] + degA * bA;
    float v01 = acc01[r] + x[(size_t)rowA * 256 + colB] + degA * bB;
    float v10 = acc10[r] + x[(size_t)rowB * 256 + colA] + degB * bA;
    float v11 = acc11[r] + x[(size_t)rowB * 256 + colB] + degB * bB;
    out[(size_t)rowA * 256 + colA] = v00;
    out[(size_t)rowA * 256 + colB] = v01;
    out[(size_t)rowB * 256 + colA] = v10;
    out[(size_t)rowB * 256 + colB] = v11;
    sA += v00 + v10; qA += v00*v00 + v10*v10;
    sB += v01 + v11; qB += v01*v01 + v11*v11;
  }
  #pragma unroll
  for (int msk = 16; msk <= 32; msk <<= 1) {
    sA += __shfl_xor(sA, msk); qA += __shfl_xor(qA, msk);
    sB += __shfl_xor(sB, msk); qB += __shfl_xor(qB, msk);
  }
  if (lane < 16) {
    atomicAdd(&bnsum[colA], sA); atomicAdd(&bnsq[colA], qA);
    atomicAdd(&bnsum[colB], sB); atomicAdd(&bnsq[colB], qB);
  }
}

// ---------------------------------------------------------------------------
__global__ __launch_bounds__(256) void bnapply_k(float* __restrict__ out,
                                                 const float* __restrict__ bnsum,
                                                 const float* __restrict__ bnsq,
                                                 const float* __restrict__ gamma,
                                                 const float* __restrict__ beta) {
  int t = threadIdx.x;
  int c4 = t & 63;
  int r = blockIdx.x * 4 + (t >> 6);
  float4 s4 = ((const float4*)bnsum)[c4];
  float4 q4 = ((const float4*)bnsq)[c4];
  float4 g4 = ((const float4*)gamma)[c4];
  float4 b4 = ((const float4*)beta)[c4];
  float4 v = ((const float4*)out)[(size_t)r * 64 + c4];
  #pragma unroll
  for (int j = 0; j < 4; ++j) {
    float mu = (&s4.x)[j] * (1.f / 8192.f);
    float var = (&q4.x)[j] * (1.f / 8192.f) - mu*mu;
    float inv = rsqrtf(var + 1e-5f);
    (&v.x)[j] = ((&v.x)[j] - mu) * inv * (&g4.x)[j] + (&b4.x)[j];
  }
  ((float4*)out)[(size_t)r * 64 + c4] = v;
}

// ---------------------------------------------------------------------------
extern "C" void kernel_launch(void* const* d_in, const int* in_sizes, int n_in,
                              void* d_out, int out_size, void* d_ws, size_t ws_size,
                              hipStream_t stream) {
  (void)in_sizes; (void)n_in; (void)out_size; (void)ws_size;
  const float* x      = (const float*)d_in[0];
  const int*   ei     = (const int*)d_in[1];
  const float* eattr  = (const float*)d_in[2];
  const int*   qm     = (const int*)d_in[3];
  const float* W_kqv  = (const float*)d_in[5];
  const float* b_kqv  = (const float*)d_in[6];
  const float* W_edge = (const float*)d_in[7];
  const float* b_edge = (const float*)d_in[8];
  const float* W_att1 = (const float*)d_in[9];
  const float* b_att1 = (const float*)d_in[10];
  const float* W_att2 = (const float*)d_in[11];
  // b_att2 cancels in softmax
  const float* W_out  = (const float*)d_in[13];
  const float* b_out  = (const float*)d_in[14];
  const float* gamma  = (const float*)d_in[15];
  const float* beta   = (const float*)d_in[16];
  float* out = (float*)d_out;

  // workspace carve-up (~27 MB)
  char* w = (char*)d_ws;
  u16*    xb      = (u16*)w;     w += (size_t)N_NODES*256*2;
  u16*    BcatT   = (u16*)w;     w += (size_t)768*256*2;
  u16*    wa1t    = (u16*)w;     w += 1024*2;
  u16*    WoutT   = (u16*)w;     w += (size_t)256*256*2;
  u16*    nodeFb  = (u16*)w;     w += (size_t)N_NODES*768*2;
  float*  biascat = (float*)w;   w += 768*4;
  float*  beW     = (float*)w;   w += 256*4;
  u16*    aggb    = (u16*)w;     w += (size_t)N_NODES*256*2;
  int*    cnt     = (int*)w;     w += N_NODES*4;
  float*  bnsum   = (float*)w;   w += 256*4;
  float*  bnsq    = (float*)w;   w += 256*4;
  int*    csr     = (int*)w;     w += (size_t)N_NODES*DEGCAP*4;
  float*  lgd     = (float*)w;   w += (size_t)NSLOT*8*4;

  // zero: cnt + bnsum + bnsq (contiguous)
  hipMemsetAsync(cnt, 0, (size_t)(N_NODES + 512) * sizeof(int), stream);

  setup_k<<<2837 + (NSLOT + 255)/256, 256, 0, stream>>>(
      x, xb, W_kqv, b_kqv, W_att1, b_att1, W_edge, b_edge, W_out,
      BcatT, biascat, wa1t, WoutT, beW, ei, qm, cnt, csr);

  gemm_nf_k<<<dim3(768/32, N_NODES/128), 256, 0, stream>>>(xb, BcatT, biascat, nodeFb);

  logits_k<<<1024 + 128, 256, 0, stream>>>(ei, qm, eattr, nodeFb, wa1t,
                                           W_edge, b_edge, W_att2, beW, lgd);

  aggr_k<<<N_NODES/4, 256, 0, stream>>>(cnt, csr, lgd, nodeFb, aggb);

  gemmout_k<<<dim3(256/32, N_NODES/128), 256, 0, stream>>>(
      aggb, WoutT, x, cnt, b_out, out, bnsum, bnsq);

  bnapply_k<<<N_NODES/4, 256, 0, stream>>>(out, bnsum, bnsq, gamma, beta);
}